// Round 8
// baseline (141.384 us; speedup 1.0000x reference)
//
#include <hip/hip_runtime.h>
#include <hip/hip_bf16.h>

#define IN_C  256
#define OUT_C 256
#define HH 56
#define WW 56
#define NN 32
#define XT_H 58
#define XT_W 64
#define WT_BYTES (8*9*256*32*2)  /* 1,179,648 B */

#define XS_BYTES 24576                /* 6 rows x 64 cols x 64B */
#define LDS_TOTAL (2*XS_BYTES)        /* 48 KiB -> 3 blocks/CU fits LDS */

using short8 = __attribute__((ext_vector_type(8))) short;
using f32x4  = __attribute__((ext_vector_type(4))) float;

__device__ __forceinline__ void gload_lds16(const void* g, void* l) {
  __builtin_amdgcn_global_load_lds((const __attribute__((address_space(1))) void*)g,
                                   (__attribute__((address_space(3))) void*)l,
                                   16, 0, 0);
}

#define VMWAIT(N) asm volatile("s_waitcnt vmcnt(" #N ")" ::: "memory")

// ---------------------------------------------------------------------------
// Fused prepass (unchanged): x transpose/convert/pad + weight convert.
// ---------------------------------------------------------------------------
__global__ void k_prep(const float* __restrict__ x, const float* __restrict__ w,
                       __hip_bfloat16* __restrict__ wt, __hip_bfloat16* __restrict__ xt) {
  const int b = blockIdx.x, tid = threadIdx.x;

  if (b >= NN * XT_H) {
    const int base = (b - NN * XT_H) * 1024;
#pragma unroll
    for (int k = 0; k < 4; ++k) {
      int idx = base + k * 256 + tid;
      int kw = idx % 3; int t1 = idx / 3;
      int kh = t1 % 3;  int t2 = t1 / 3;
      int ic = t2 % IN_C; int oc = t2 / IN_C;
      int tap = kh * 3 + kw;
      wt[((((ic >> 5) * 9 + tap) * 256 + oc) * 32) + (ic & 31)] = __float2bfloat16(w[idx]);
    }
    return;
  }

  const int n = b / XT_H, hp = b % XT_H;
  __hip_bfloat16* row = xt + (size_t)(n * XT_H + hp) * XT_W * 256;

  if (hp == 0 || hp == XT_H - 1) {
    int4 z; z.x = z.y = z.z = z.w = 0;
#pragma unroll
    for (int k = 0; k < 8; ++k) ((int4*)row)[k * 256 + tid] = z;
    return;
  }

  const int h = hp - 1;
  __shared__ __hip_bfloat16 tile[56][264];

  {
    const int ic = tid;
    const float* src = x + (((size_t)n * IN_C + ic) * HH + h) * WW;
#pragma unroll
    for (int j = 0; j < 14; ++j) {
      float4 v = ((const float4*)src)[j];
      tile[4 * j + 0][ic] = __float2bfloat16(v.x);
      tile[4 * j + 1][ic] = __float2bfloat16(v.y);
      tile[4 * j + 2][ic] = __float2bfloat16(v.z);
      tile[4 * j + 3][ic] = __float2bfloat16(v.w);
    }
  }
  {
    int4 z; z.x = z.y = z.z = z.w = 0;
    int cell = tid >> 5, s = tid & 31;
    int wp = (cell == 0) ? 0 : (56 + cell);
    ((int4*)(row + (size_t)wp * 256))[s] = z;
  }
  __syncthreads();
#pragma unroll
  for (int k = 0; k < 7; ++k) {
    int e = k * 256 + tid;
    int wq = e >> 5, seg = e & 31;
    short8 v = *(const short8*)&tile[wq][seg * 8];
    *(short8*)(row + (size_t)(wq + 1) * 256 + seg * 8) = v;
  }
}

// ---------------------------------------------------------------------------
// main conv: block = 4 waves, 224 px x 64 oc; wave = 112 px x 32 oc.
// 3 blocks/CU (launch_bounds(256,3), ~140 regs/lane incl. 56 acc).
// Grid = 1792 = exactly 7 blocks/CU -> no tail quantization.
// Weights global(L2)->VGPR rolling 3-slot (2 loads/phase, lookahead 2 groups).
// LDS holds only x (double-buffered). 8 barriers; vmcnt(2) at chunk boundary.
// ---------------------------------------------------------------------------
__global__ __launch_bounds__(256, 3) void k_conv(
    const __hip_bfloat16* __restrict__ wt, const __hip_bfloat16* __restrict__ xt,
    const float* __restrict__ bias, float* __restrict__ out) {
  extern __shared__ __align__(16) char lds[];
  char* xs_c = lds;                    // [2][row6][col64][64B]

  const int tid  = threadIdx.x;
  const int wid  = tid >> 6, lane = tid & 63;
  const int cc   = lane & 15, g = lane >> 4;
  const int wn   = wid & 1,  wm = wid >> 1;

  // XCD-bijective swizzle (1792 % 8 == 0). Consecutive work ids share (n,q)
  // across the 4 oh-siblings -> same XCD -> shared x-tile L2 hits.
  const int work = (blockIdx.x & 7) * 224 + (blockIdx.x >> 3);
  const int n   = work / 56;
  const int rem = work - n * 56;
  const int q   = rem >> 2, oh = rem & 3;
  const int h0  = q * 4;

  int xoff[7];
#pragma unroll
  for (int pt = 0; pt < 7; ++pt) {
    int p = wm * 112 + pt * 16 + cc;
    int rp = p / 56, wp = p - rp * 56;
    xoff[pt] = rp * 4096 + wp * 64 + g * 16;
  }
  const int ocb = oh * 64 + wn * 32;                 // wave's oc base
  const __hip_bfloat16* wlane = wt + (size_t)(ocb + cc) * 32 + g * 8;

  f32x4 acc[2][7];
#pragma unroll
  for (int a = 0; a < 2; ++a)
#pragma unroll
    for (int bb = 0; bb < 7; ++bb) acc[a][bb] = (f32x4){0.f, 0.f, 0.f, 0.f};

  const __hip_bfloat16* xtn = xt + (size_t)(n * XT_H + h0) * XT_W * 256;

  auto stage_x = [&](int buf, int ch) {
#pragma unroll
    for (int i = 0; i < 6; ++i) {
      int s = wid * 6 + i;
      int rowc = s >> 2, colq = s & 3;
      const __hip_bfloat16* src = xtn + (size_t)(rowc * 64 + colq * 16 + (lane >> 2)) * 256
                                      + ch * 32 + (lane & 3) * 8;
      gload_lds16(src, xs_c + buf * XS_BYTES + rowc * 4096 + colq * 1024);
    }
  };
  auto loadw1 = [&](int ph, int oct) -> short8 {
    return *(const short8*)(wlane + (size_t)ph * 8192 + oct * 512);
  };

  short8 wA, wB, wC;

  // prologue: x(0) DMA first (FIFO-oldest), then phase-0 weights
  stage_x(0, 0);
  __builtin_amdgcn_sched_barrier(0);
  wA = loadw1(0, 0);
  wB = loadw1(0, 1);

#define MFMA7(W_, oct_) do {                                                          \
    __builtin_amdgcn_s_setprio(1);                                                    \
    _Pragma("unroll")                                                                 \
    for (int pt = 0; pt < 7; ++pt)                                                    \
      acc[oct_][pt] = __builtin_amdgcn_mfma_f32_16x16x32_bf16(W_, xf[pt], acc[oct_][pt], 0, 0, 0); \
    __builtin_amdgcn_s_setprio(0);                                                    \
  } while (0)

  // Enter with T0_ = oct0(ph), T1_ = oct1(ph). Loads: T2_ = oct0(ph+1) before
  // group0; T0_ = oct1(ph+1) after group0. Rotation period 3; 9 phases/chunk
  // returns to identity for the next chunk.
#define PHASE(ph_, kh_, kw_, T0_, T1_, T2_) do {                                      \
    short8 xf[7];                                                                     \
    _Pragma("unroll")                                                                 \
    for (int pt = 0; pt < 7; ++pt)                                                    \
      xf[pt] = *(const short8*)(xb + xoff[pt] + (kh_) * 4096 + (kw_) * 64);           \
    T2_ = loadw1((ph_) + 1, 0);                                                       \
    MFMA7(T0_, 0);                                                                    \
    T0_ = loadw1((ph_) + 1, 1);                                                       \
    MFMA7(T1_, 1);                                                                    \
  } while (0)

  for (int ch = 0; ch < 8; ++ch) {
    // newest 2 in flight = rolling w loads; everything older (x DMA) drained
    VMWAIT(2);
    __builtin_amdgcn_s_barrier();
    if (ch < 7) {
      stage_x((ch + 1) & 1, ch + 1);
      __builtin_amdgcn_sched_barrier(0);
    }
    const char* xb = xs_c + ((ch & 1) ? XS_BYTES : 0);
    const int ph0 = ch * 9;
    PHASE(ph0 + 0, 0, 0, wA, wB, wC);
    PHASE(ph0 + 1, 0, 1, wC, wA, wB);
    PHASE(ph0 + 2, 0, 2, wB, wC, wA);
    PHASE(ph0 + 3, 1, 0, wA, wB, wC);
    PHASE(ph0 + 4, 1, 1, wC, wA, wB);
    PHASE(ph0 + 5, 1, 2, wB, wC, wA);
    PHASE(ph0 + 6, 2, 0, wA, wB, wC);
    PHASE(ph0 + 7, 2, 1, wC, wA, wB);
    PHASE(ph0 + 8, 2, 2, wB, wC, wA);
  }
#undef PHASE
#undef MFMA7

  // epilogue: D row(4g+r)=oc, D col(cc)=pixel -> coalesced stores over cc
  int rp_[7], wp_[7];
#pragma unroll
  for (int pt = 0; pt < 7; ++pt) {
    int p = wm * 112 + pt * 16 + cc;
    rp_[pt] = p / 56; wp_[pt] = p - rp_[pt] * 56;
  }
#pragma unroll
  for (int oct = 0; oct < 2; ++oct) {
    const int oc0 = ocb + oct * 16 + 4 * g;
#pragma unroll
    for (int r = 0; r < 4; ++r) {
      const float bv = bias[oc0 + r];
      const size_t obase = ((size_t)n * OUT_C + (oc0 + r)) * (HH * WW);
#pragma unroll
      for (int pt = 0; pt < 7; ++pt)
        out[obase + (size_t)(h0 + rp_[pt]) * 56 + wp_[pt]] = acc[oct][pt][r] + bv;
    }
  }
}

extern "C" void kernel_launch(void* const* d_in, const int* in_sizes, int n_in,
                              void* d_out, int out_size, void* d_ws, size_t ws_size,
                              hipStream_t stream) {
  const float* x    = (const float*)d_in[0];
  const float* w    = (const float*)d_in[1];
  const float* bias = (const float*)d_in[2];
  float* out        = (float*)d_out;

  __hip_bfloat16* wt = (__hip_bfloat16*)d_ws;
  __hip_bfloat16* xt = (__hip_bfloat16*)((char*)d_ws + WT_BYTES);

  hipFuncSetAttribute((const void*)k_conv,
                      hipFuncAttributeMaxDynamicSharedMemorySize, LDS_TOTAL);

  k_prep<<<NN * XT_H + 576, 256, 0, stream>>>(x, w, wt, xt);
  k_conv<<<NN * 14 * 4, 256, LDS_TOTAL, stream>>>(wt, xt, bias, out);
}